// Round 8
// baseline (180.065 us; speedup 1.0000x reference)
//
#include <hip/hip_runtime.h>
#include <math.h>

constexpr int L = 32768;
constexpr int H = 256;
constexpr int P = 256;
constexpr int T = 64;        // scan chunk length == row tile
constexpr int NC = L / T;    // 512 chunks
constexpr int N1 = 2 * P;    // 512 cat width, col = 2p+{0:re,1:im}
constexpr int LDEP = 66;     // epilogue LDS row stride (floats), 64 cols + pad

typedef __attribute__((ext_vector_type(8))) short short8;
typedef __attribute__((ext_vector_type(4))) float f32x4;

// ---------------- bf16 helpers (RNE) ----------------
__device__ __forceinline__ unsigned f2bf(float f) {
  unsigned u = __float_as_uint(f);
  return (u + 0x7FFFu + ((u >> 16) & 1u)) >> 16;
}
__device__ __forceinline__ float bf_lo(unsigned u) { return __uint_as_float(u << 16); }
__device__ __forceinline__ float bf_hi(unsigned u) { return __uint_as_float(u & 0xFFFF0000u); }

__device__ __forceinline__ void lambda_bar_of(const float* __restrict__ lam,
                                              const float* __restrict__ lstep,
                                              int p, float& lbr, float& lbi) {
  float lr = lam[2 * p], li = lam[2 * p + 1];
  float st = expf(lstep[p]);
  float ea = expf(lr * st);
  lbr = ea * cosf(li * st);
  lbi = ea * sinf(li * st);
}

// fixup: one packed bf16 pair (re,im) += pow*carry (complex, fp32)
__device__ __forceinline__ unsigned fix2(unsigned w, float pr, float pi, float cr, float ci) {
  float xgr = fmaf(pr, cr, fmaf(-pi, ci, bf_lo(w)));
  float xgi = fmaf(pr, ci, fmaf(pi, cr, bf_hi(w)));
  return f2bf(xgr) | (f2bf(xgi) << 16);
}

// ===========================================================================
// Swizzled fragment layout (16x16x32 bf16 MFMA):
//   slab(r16, kb) = 64 lanes x 16 B; lane = (row&15) + 16*((k>>3)&3),
//   lane's 8 elements are k = kb*32 + (lane>>4)*8 + 0..7.
//   Slab index = r16*(K/32)+kb; wave load = slab*1024B + lane*16B (coalesced).
// ===========================================================================

// ---------------------------------------------------------------------------
// k_prep: builds everything swizzled.
//  bx <  2048 : sig fp32 -> Asw (bf16, swizzled) via LDS transpose
//  bx <  2112 : Bsw  (N1 x 256, swizzled B_bar cat rows 2p/2p+1 = Re/Im)
//  bx <  2176 : Csw  (256 x N1, swizzled C cat cols 2p/2p+1 = Re/-Im)
//  bx <  2208 : powsw (fp32, pair-interleaved, A-frag swizzled, t16 x kb slabs)
// ---------------------------------------------------------------------------
__global__ __launch_bounds__(256) void k_prep(const float* __restrict__ sig,
                                              const float* __restrict__ lam,
                                              const float* __restrict__ lstep,
                                              const float* __restrict__ Bri,
                                              const float* __restrict__ Cri,
                                              unsigned short* __restrict__ Asw,
                                              unsigned short* __restrict__ Bsw,
                                              unsigned short* __restrict__ Csw,
                                              float* __restrict__ powsw) {
  __shared__ __align__(16) unsigned short plds[16 * 272];
  const int tid = threadIdx.x, bx = blockIdx.x;
  if (bx < 2048) {  // one 16-row band of sig
    const float4* sig4 = (const float4*)sig;
    size_t fb = (size_t)bx * 1024;
#pragma unroll
    for (int u = 0; u < 4; u++) {
      int idx = u * 256 + tid;
      float4 a = sig4[fb + idx];
      int row = idx >> 6, colf = (idx & 63) * 4;
      uint2 w;
      w.x = f2bf(a.x) | (f2bf(a.y) << 16);
      w.y = f2bf(a.z) | (f2bf(a.w) << 16);
      *(uint2*)(plds + row * 272 + colf) = w;
    }
    __syncthreads();
    uint4* dst = (uint4*)Asw + (size_t)bx * 512;
#pragma unroll
    for (int u = 0; u < 2; u++) {
      int s = u * 256 + tid;
      int kb = s >> 6, ln = s & 63;
      int row = ln & 15, k0 = kb * 32 + (ln >> 4) * 8;
      dst[s] = *(const uint4*)(plds + row * 272 + k0);
    }
    return;
  }
  if (bx < 2112) {  // Bsw
    int o = (bx - 2048) * 256 + tid;  // < 16384 uint4 slots
    int slab = o >> 6, ln = o & 63;
    int n16 = slab >> 3, kb = slab & 7;
    int n = n16 * 16 + (ln & 15);
    int k0 = kb * 32 + (ln >> 4) * 8;
    int p = n >> 1, comp = n & 1;
    float lr = lam[2 * p], li = lam[2 * p + 1];
    float st = expf(lstep[p]);
    float ea = expf(lr * st);
    float lbr = ea * cosf(li * st), lbi = ea * sinf(li * st);
    float inv = 1.0f / (lr * lr + li * li);
    float nr = lbr - 1.0f;
    float fr = (nr * lr + lbi * li) * inv, fi = (lbi * lr - nr * li) * inv;
    unsigned wv[4];
#pragma unroll
    for (int m = 0; m < 4; m++) {
      unsigned lh[2];
#pragma unroll
      for (int h2 = 0; h2 < 2; h2++) {
        int k = k0 + m * 2 + h2;
        float br = Bri[2 * (p * H + k)], bi = Bri[2 * (p * H + k) + 1];
        float v = comp ? (fr * bi + fi * br) : (fr * br - fi * bi);
        lh[h2] = f2bf(v);
      }
      wv[m] = lh[0] | (lh[1] << 16);
    }
    uint4 w; w.x = wv[0]; w.y = wv[1]; w.z = wv[2]; w.w = wv[3];
    ((uint4*)Bsw)[o] = w;
    return;
  }
  if (bx < 2176) {  // Csw
    int o = (bx - 2112) * 256 + tid;  // < 16384
    int slab = o >> 6, ln = o & 63;
    int h16 = slab >> 4, kb = slab & 15;
    int h = h16 * 16 + (ln & 15);
    int k0 = kb * 32 + (ln >> 4) * 8;
    unsigned wv[4];
#pragma unroll
    for (int m = 0; m < 4; m++) {
      unsigned lh[2];
#pragma unroll
      for (int h2 = 0; h2 < 2; h2++) {
        int kcat = k0 + m * 2 + h2;
        int p = kcat >> 1;
        float v = (kcat & 1) ? -Cri[2 * (h * P + p) + 1] : Cri[2 * (h * P + p)];
        lh[h2] = f2bf(v);
      }
      wv[m] = lh[0] | (lh[1] << 16);
    }
    uint4 w; w.x = wv[0]; w.y = wv[1]; w.z = wv[2]; w.w = wv[3];
    ((uint4*)Csw)[o] = w;
    return;
  }
  {  // powsw: lambda^(t+1), fp32, pair-interleaved, swizzled
    int o = (bx - 2176) * 256 + tid;  // < 8192 float4 slots
    int s = o >> 1, half = o & 1;
    int ln = s & 63, slab = s >> 6;
    int t16 = slab >> 4, kb = slab & 15;
    int t = t16 * 16 + (ln & 15);
    int kbase = kb * 32 + (ln >> 4) * 8 + half * 4;
    float e = (float)(t + 1);
    float4 v;
    {
      int p = kbase >> 1;
      float lr = lam[2 * p], li = lam[2 * p + 1], st = expf(lstep[p]);
      float er = expf(e * lr * st);
      v.x = er * cosf(e * li * st);
      v.y = er * sinf(e * li * st);
    }
    {
      int p = (kbase >> 1) + 1;
      float lr = lam[2 * p], li = lam[2 * p + 1], st = expf(lstep[p]);
      float er = expf(e * lr * st);
      v.z = er * cosf(e * li * st);
      v.w = er * sinf(e * li * st);
    }
    ((float4*)powsw)[o] = v;
  }
}

// ---------------------------------------------------------------------------
// GEMM1: Bu tile = Asw(sig) @ Bsw^T. Barrier-free K-loop, coalesced swizzled
// fragment loads. Tile 64x64 (1 chunk x 32 pairs), 4 waves of 16x64 rows.
// Epilogue LDS 16.9 KB -> ~6 blocks/CU. grid (8, 512).
// ---------------------------------------------------------------------------
__global__ __launch_bounds__(256) void k_gemm1(const unsigned short* __restrict__ Asw,
                                               const unsigned short* __restrict__ Bsw,
                                               const float* __restrict__ lam,
                                               const float* __restrict__ lstep,
                                               unsigned short* __restrict__ Xsw,
                                               float* __restrict__ Sr,
                                               float* __restrict__ Si) {
  __shared__ __align__(16) float sEpi[T * LDEP];  // 16.9 KB
  const int tid = threadIdx.x, lane = tid & 63, wave = tid >> 6;
  const int c = blockIdx.y, n0 = blockIdx.x * 64;
  const unsigned short* Ab = Asw + ((size_t)(c * 4 + wave) * 8) * 512 + lane * 8;
  const unsigned short* Bb = Bsw + ((size_t)(n0 >> 4) * 8) * 512 + lane * 8;
  f32x4 acc[4];
#pragma unroll
  for (int j = 0; j < 4; j++) acc[j] = (f32x4){0.f, 0.f, 0.f, 0.f};

#pragma unroll
  for (int kb = 0; kb < 8; kb++) {
    short8 af = *(const short8*)(Ab + kb * 512);
    short8 bf[4];
#pragma unroll
    for (int j = 0; j < 4; j++) bf[j] = *(const short8*)(Bb + j * 8 * 512 + kb * 512);
#pragma unroll
    for (int j = 0; j < 4; j++)
      acc[j] = __builtin_amdgcn_mfma_f32_16x16x32_bf16(af, bf[j], acc[j], 0, 0, 0);
  }

  // epilogue: dump (C-layout) then chunk-local scan
  const int crow = (lane >> 4) * 4, ccol = lane & 15;
#pragma unroll
  for (int j = 0; j < 4; j++)
#pragma unroll
    for (int g = 0; g < 4; g++)
      sEpi[(wave * 16 + crow + g) * LDEP + (j * 16 + ccol)] = acc[j][g];
  __syncthreads();

  if (tid < 32) {
    const int pl = tid;                 // local pair 0..31
    const int gp = (n0 >> 1) + pl;
    float lbr, lbi;
    lambda_bar_of(lam, lstep, gp, lbr, lbi);
    const int kbx = (n0 >> 5) + (pl >> 4);
    const int slot16 = 16 * ((pl >> 2) & 3);
    const int off2 = (pl & 3) * 2;
    float xr = 0.f, xi = 0.f;
    const float* e = sEpi + 2 * pl;
    for (int tb = 0; tb < T; tb += 8) {
      float2 v[8];
#pragma unroll
      for (int u = 0; u < 8; u++) v[u] = *(const float2*)(e + (tb + u) * LDEP);
      unsigned ov[8];
#pragma unroll
      for (int u = 0; u < 8; u++) {
        float nr = fmaf(lbr, xr, fmaf(-lbi, xi, v[u].x));
        float ni = fmaf(lbr, xi, fmaf(lbi, xr, v[u].y));
        xr = nr; xi = ni;
        ov[u] = f2bf(xr) | (f2bf(xi) << 16);
      }
      size_t slabbase = ((size_t)(c * 4 + (tb >> 4)) * 16 + kbx) * 512;
#pragma unroll
      for (int u = 0; u < 8; u++)
        *(unsigned*)(Xsw + slabbase + ((tb & 15) + u + slot16) * 8 + off2) = ov[u];
    }
    Sr[c * P + gp] = xr;
    Si[c * P + gp] = xi;
  }
}

// ---------------------------------------------------------------------------
// Parallel carry scan: 256 blocks (one per p) x 64 threads (1 wave).
// Lane t: 8 chunks local Horner -> wave segment-scan (shfl) -> exclusive
// carry -> apply + store interleaved carcat[c*512 + 2p] = (re, im).
// ---------------------------------------------------------------------------
__global__ __launch_bounds__(64) void k_carry2(const float* __restrict__ lam,
                                               const float* __restrict__ lstep,
                                               const float* __restrict__ Sr,
                                               const float* __restrict__ Si,
                                               float* __restrict__ carcat) {
  const int p = blockIdx.x;
  const int t = threadIdx.x;  // 0..63
  float lr = lam[2 * p], li = lam[2 * p + 1];
  float st = expf(lstep[p]);
  float eT = expf((float)T * lr * st);
  float lTr = eT * cosf((float)T * li * st);
  float lTi = eT * sinf((float)T * li * st);
  float vr[8], vi[8];
#pragma unroll
  for (int u = 0; u < 8; u++) {
    vr[u] = Sr[(t * 8 + u) * P + p];
    vi[u] = Si[(t * 8 + u) * P + p];
  }
  float Br = 0.f, Bi = 0.f;
#pragma unroll
  for (int u = 0; u < 8; u++) {
    float nr = fmaf(lTr, Br, fmaf(-lTi, Bi, vr[u]));
    float ni = fmaf(lTr, Bi, fmaf(lTi, Br, vi[u]));
    Br = nr; Bi = ni;
  }
  float e8 = expf(8.0f * (float)T * lr * st);
  float Ar = e8 * cosf(8.0f * (float)T * li * st);
  float Ai = e8 * sinf(8.0f * (float)T * li * st);
#pragma unroll
  for (int d = 1; d < 64; d <<= 1) {
    float Aor = __shfl_up(Ar, d), Aoi = __shfl_up(Ai, d);
    float Bor = __shfl_up(Br, d), Boi = __shfl_up(Bi, d);
    if (t >= d) {
      float nBr = Ar * Bor - Ai * Boi + Br;
      float nBi = Ar * Boi + Ai * Bor + Bi;
      float nAr = Aor * Ar - Aoi * Ai;
      float nAi = Aor * Ai + Aoi * Ar;
      Br = nBr; Bi = nBi; Ar = nAr; Ai = nAi;
    }
  }
  float cr = __shfl_up(Br, 1), ci = __shfl_up(Bi, 1);
  if (t == 0) { cr = 0.f; ci = 0.f; }
#pragma unroll
  for (int u = 0; u < 8; u++) {
    *(float2*)(carcat + (size_t)(t * 8 + u) * N1 + 2 * p) = make_float2(cr, ci);
    float nr = fmaf(lTr, cr, fmaf(-lTi, ci, vr[u]));
    float ni = fmaf(lTr, ci, fmaf(lTi, cr, vi[u]));
    cr = nr; ci = ni;
  }
}

// ---------------------------------------------------------------------------
// GEMM2: y = (Xsw + pow*carry) @ Csw^T + D*u. Barrier-free, zero LDS,
// coalesced swizzled loads. Tile 64x64 (1 chunk x 64 h), 4 waves of 16x64.
// grid (4, 512) = 2048 blocks -> ~6 blocks/CU resident.
// ---------------------------------------------------------------------------
__global__ __launch_bounds__(256) void k_gemm2(const unsigned short* __restrict__ Xsw,
                                               const unsigned short* __restrict__ Csw,
                                               const float* __restrict__ powsw,
                                               const float* __restrict__ carcat,
                                               const float* __restrict__ sig,
                                               const float* __restrict__ Dv,
                                               float* __restrict__ out) {
  const int tid = threadIdx.x, lane = tid & 63, wave = tid >> 6;
  const int c = blockIdx.y, n0 = blockIdx.x * 64;
  const int m0 = c * 64;
  const unsigned short* Ab = Xsw + ((size_t)(c * 4 + wave) * 16) * 512 + lane * 8;
  const unsigned short* Bb = Csw + ((size_t)(n0 >> 4) * 16) * 512 + lane * 8;
  const float* Pw = powsw + ((size_t)wave * 16) * 512 + lane * 8;
  const float* Cw = carcat + (size_t)c * N1 + (lane >> 4) * 8;
  f32x4 acc[4];
#pragma unroll
  for (int j = 0; j < 4; j++) acc[j] = (f32x4){0.f, 0.f, 0.f, 0.f};

#pragma unroll 4
  for (int kb = 0; kb < 16; kb++) {
    uint4 x0 = *(const uint4*)(Ab + kb * 512);
    float4 pa = *(const float4*)(Pw + kb * 512);
    float4 pb = *(const float4*)(Pw + kb * 512 + 4);
    float4 ca = *(const float4*)(Cw + kb * 32);
    float4 cb = *(const float4*)(Cw + kb * 32 + 4);
    short8 bf[4];
#pragma unroll
    for (int j = 0; j < 4; j++) bf[j] = *(const short8*)(Bb + j * 16 * 512 + kb * 512);
    union { short8 s; uint4 u; } A0;
    A0.u.x = fix2(x0.x, pa.x, pa.y, ca.x, ca.y);
    A0.u.y = fix2(x0.y, pa.z, pa.w, ca.z, ca.w);
    A0.u.z = fix2(x0.z, pb.x, pb.y, cb.x, cb.y);
    A0.u.w = fix2(x0.w, pb.z, pb.w, cb.z, cb.w);
#pragma unroll
    for (int j = 0; j < 4; j++)
      acc[j] = __builtin_amdgcn_mfma_f32_16x16x32_bf16(A0.s, bf[j], acc[j], 0, 0, 0);
  }

  const int crow = (lane >> 4) * 4, ccol = lane & 15;
  float dcol[4];
#pragma unroll
  for (int j = 0; j < 4; j++) dcol[j] = Dv[n0 + ccol + j * 16];
#pragma unroll
  for (int j = 0; j < 4; j++) {
    int col = n0 + ccol + j * 16;
#pragma unroll
    for (int g = 0; g < 4; g++) {
      int row = m0 + wave * 16 + crow + g;
      out[(size_t)row * H + col] = acc[j][g] + dcol[j] * sig[(size_t)row * H + col];
    }
  }
}

// ---------------------------------------------------------------------------
// Launch
// ---------------------------------------------------------------------------
extern "C" void kernel_launch(void* const* d_in, const int* in_sizes, int n_in,
                              void* d_out, int out_size, void* d_ws, size_t ws_size,
                              hipStream_t stream) {
  const float* sig = (const float*)d_in[0];   // (L,H)
  const float* lam = (const float*)d_in[1];   // (P,2)
  const float* Bri = (const float*)d_in[2];   // (P,H,2)
  const float* Cri = (const float*)d_in[3];   // (H,P,2)
  const float* Dv  = (const float*)d_in[4];   // (H,)
  const float* lst = (const float*)d_in[5];   // (P,)
  float* out = (float*)d_out;

  // workspace (~53 MB)
  unsigned short* Asw = (unsigned short*)d_ws;        // L*H shorts (16 MB)
  unsigned short* Xsw = Asw + (size_t)L * H;          // L*N1 shorts (32 MB)
  unsigned short* Bsw = Xsw + (size_t)L * N1;         // N1*H shorts
  unsigned short* Csw = Bsw + (size_t)N1 * H;         // H*N1 shorts
  float* powsw  = (float*)(Csw + (size_t)H * N1);     // 64*512 floats
  float* Sr     = powsw + 64 * 512;                   // NC*P
  float* Si     = Sr + NC * P;
  float* carcat = Si + NC * P;                        // NC*N1 floats (1 MB)

  k_prep<<<2208, 256, 0, stream>>>(sig, lam, lst, Bri, Cri, Asw, Bsw, Csw, powsw);
  dim3 g1(N1 / 64, NC);
  k_gemm1<<<g1, 256, 0, stream>>>(Asw, Bsw, lam, lst, Xsw, Sr, Si);
  k_carry2<<<P, 64, 0, stream>>>(lam, lst, Sr, Si, carcat);
  dim3 g2(H / 64, NC);
  k_gemm2<<<g2, 256, 0, stream>>>(Xsw, Csw, powsw, carcat, sig, Dv, out);
}